// Round 5
// baseline (242.125 us; speedup 1.0000x reference)
//
#include <hip/hip_runtime.h>
#include <hip/hip_cooperative_groups.h>
#include <cstdint>
#include <cstddef>

// B=32 batch, K=4096 complex input pixels, N=4096 complex outputs.
// out[b,n] = sum_k (e_in[b,k]*ts[k]) * w[k,n]   (complex)
// Real-GEMM formulation, K'=8192 interleaved (re,im):
//   A[b][2k]=m_re, A[b][2k+1]=m_im
//   B_re[2k][n]=w_re, B_re[2k+1][n]=-w_im  -> out_re
//   B_im[2k][n]=w_im, B_im[2k+1][n]= w_re  -> out_im
// OUTPUT (established R5): float32 PLANAR — [re-plane 131072][im-plane 131072].
//
// R10: single cooperative kernel. R5-R9: five structurally different gemm
// variants all pinned at 49-55us while (total - gemm) stayed ~114us across
// rounds; prep+reduce account for ~10us of that -> ~100us is inter-dispatch
// overhead in the timed region. Fuse prep / gemm / reduce into one
// cooperative launch with two grid.sync()s. Gemm body is R9's verbatim
// (numerics proven). Fallback to the 3-kernel path if cooperative launch
// is rejected.
#define KC 4096
#define NN 4096
#define NB 32
#define HALF (NB * NN)
#define KB 32            // complex k per big step

typedef __attribute__((ext_vector_type(8))) short  bf16x8;  // 8 bf16 (4 VGPRs)
typedef __attribute__((ext_vector_type(16))) float f32x16;  // 32x32 MFMA acc

__device__ __forceinline__ unsigned short f2bf(float f) {
    union { float f; unsigned u; } v; v.f = f;
    unsigned r = v.u + 0x7fffu + ((v.u >> 16) & 1u);
    return (unsigned short)(r >> 16);
}

// ---------------------------------------------------------------------------
// Phase bodies (shared by fused and fallback kernels)
// ---------------------------------------------------------------------------
__device__ __forceinline__ void prep_body(
    int gtid, const float* __restrict__ in_re, const float* __restrict__ in_im,
    const float* __restrict__ amp, const float* __restrict__ phase,
    uint32_t* __restrict__ wsA)
{
    int b = gtid >> 12;
    int k = gtid & (KC - 1);
    float er = in_re[gtid], ei = in_im[gtid];
    float a = amp[k], p = phase[k];
    float s = 1.0f / (1.0f + __expf(-a));
    float sn = __sinf(p);
    float cs = __cosf(p);
    float tr = s * cs, ti = s * sn;
    float mr = er * tr - ei * ti;
    float mi = er * ti + ei * tr;
    uint32_t pk = (uint32_t)f2bf(mr) | ((uint32_t)f2bf(mi) << 16);
    wsA[((((k >> 2) << 5) + b) << 2) | (k & 3)] = pk;
}

// ---------------------------------------------------------------------------
// Fused cooperative kernel. Grid: dim3(16*S), block 512. 1 block/CU (136 KB
// LDS) -> all 256 blocks co-resident.
// Gemm (phase 1) = R9 structure: 8 waves x 32 n-cols = 256-wide n-tile,
// K-step 32 complex, double-buffered LDS, glds staging (10 VMEM/wave/step),
// counted vmcnt(10), raw s_barriers.
// ---------------------------------------------------------------------------
__global__ __launch_bounds__(512) void fused_kernel(
    const float* __restrict__ in_re, const float* __restrict__ in_im,
    const float* __restrict__ amp,   const float* __restrict__ phase,
    const float* __restrict__ w_re,  const float* __restrict__ w_im,
    uint32_t* __restrict__ wsA, float2* __restrict__ wsP,
    float* __restrict__ out, int S, int steps)
{
    cooperative_groups::grid_group grid = cooperative_groups::this_grid();

    __shared__ float    ldsW[2][2][KB][256];   // [buf][re/im][k][n]  128 KB
    __shared__ uint32_t ldsA[2][KB * 32];      // [buf][1024 dw]        8 KB

    const int tid    = threadIdx.x;
    const int nblk   = gridDim.x;
    const int gthr   = nblk * 512;

    // ---- phase 0: prep (grid-stride; NB*KC = 131072 elements) ----
    for (int g = blockIdx.x * 512 + tid; g < NB * KC; g += gthr)
        prep_body(g, in_re, in_im, amp, phase, wsA);

    grid.sync();

    // ---- phase 1: gemm (R9 verbatim, blockIdx decomposed) ----
    {
        const int bidx = blockIdx.x & 15;   // n-slice
        const int s    = blockIdx.x >> 4;   // k-split
        const int lane = tid & 63;
        const int wave = tid >> 6;          // 0..7
        const int h    = lane >> 5;         // K'-octet half
        const int l32  = lane & 31;         // n within wave's 32-col slice
        const int n    = bidx * 256 + wave * 32 + l32;
        const int kbase = s * (steps * KB); // complex-k base of this split

        // W staging: per (wave, j=0..3) one full row (row = j*8+wave, 1 KB);
        // lane supplies bytes lane*16 (glds dest = wave-uniform base + lane*16).
        const float* gW_re = w_re + (size_t)kbase * NN + bidx * 256 + (lane << 2);
        const float* gW_im = w_im + (size_t)kbase * NN + bidx * 256 + (lane << 2);
        // A staging: per (wave, j=0..1) one 256-B chunk c = wave*2+j (64 dw).
        const uint32_t* gA = wsA + (size_t)(kbase >> 2) * 128 + lane;

        f32x16 accR = {};
        f32x16 accI = {};

        auto STAGE = [&](int t, int bb) {
#pragma unroll
            for (int j = 0; j < 4; ++j) {
                int row = j * 8 + wave;
                __builtin_amdgcn_global_load_lds(
                    (const __attribute__((address_space(1))) void*)(gW_re + (size_t)(t * KB + row) * NN),
                    (__attribute__((address_space(3))) void*)(&ldsW[bb][0][row][0]),
                    16, 0, 0);
            }
#pragma unroll
            for (int j = 0; j < 4; ++j) {
                int row = j * 8 + wave;
                __builtin_amdgcn_global_load_lds(
                    (const __attribute__((address_space(1))) void*)(gW_im + (size_t)(t * KB + row) * NN),
                    (__attribute__((address_space(3))) void*)(&ldsW[bb][1][row][0]),
                    16, 0, 0);
            }
#pragma unroll
            for (int j = 0; j < 2; ++j) {
                int c = wave * 2 + j;
                __builtin_amdgcn_global_load_lds(
                    (const __attribute__((address_space(1))) void*)(gA + (size_t)t * (KB * 32) + c * 64),
                    (__attribute__((address_space(3))) void*)(&ldsA[bb][c * 64]),
                    4, 0, 0);
            }
        };

        auto COMPUTE = [&](int bb) {
#pragma unroll
            for (int ss = 0; ss < 4; ++ss) {
                bf16x8 afrag = *(const bf16x8*)&ldsA[bb][ss * 256 + h * 128 + l32 * 4];
                const float* Lre = &ldsW[bb][0][ss * 8 + h * 4][wave * 32 + l32];
                const float* Lim = &ldsW[bb][1][ss * 8 + h * 4][wave * 32 + l32];
                float r0 = Lre[0], r1 = Lre[256], r2 = Lre[512], r3 = Lre[768];
                float i0 = Lim[0], i1 = Lim[256], i2 = Lim[512], i3 = Lim[768];

                // f2bf(-x) == f2bf(x)^0x8000 exactly (RNE is sign-symmetric).
                unsigned short br0 = f2bf(r0), br1 = f2bf(r1), br2 = f2bf(r2), br3 = f2bf(r3);
                unsigned short bi0 = f2bf(i0), bi1 = f2bf(i1), bi2 = f2bf(i2), bi3 = f2bf(i3);
                bf16x8 bR, bI;
                bR[0] = (short)br0;  bR[1] = (short)(bi0 ^ 0x8000);
                bR[2] = (short)br1;  bR[3] = (short)(bi1 ^ 0x8000);
                bR[4] = (short)br2;  bR[5] = (short)(bi2 ^ 0x8000);
                bR[6] = (short)br3;  bR[7] = (short)(bi3 ^ 0x8000);
                bI[0] = (short)bi0;  bI[1] = (short)br0;
                bI[2] = (short)bi1;  bI[3] = (short)br1;
                bI[4] = (short)bi2;  bI[5] = (short)br2;
                bI[6] = (short)bi3;  bI[7] = (short)br3;

                accR = __builtin_amdgcn_mfma_f32_32x32x16_bf16(afrag, bR, accR, 0, 0, 0);
                accI = __builtin_amdgcn_mfma_f32_32x32x16_bf16(afrag, bI, accI, 0, 0, 0);
            }
        };

        STAGE(0, 0);
        for (int t = 0; t < steps - 1; ++t) {
            STAGE(t + 1, (t + 1) & 1);
            // Wait own 10 oldest (tile t) done; tile t+1's 10 stay in flight.
            asm volatile("s_waitcnt vmcnt(10)" ::: "memory");
            __builtin_amdgcn_s_barrier();
            COMPUTE(t & 1);
            __builtin_amdgcn_s_barrier();
        }
        asm volatile("s_waitcnt vmcnt(0)" ::: "memory");
        __builtin_amdgcn_s_barrier();
        COMPUTE((steps - 1) & 1);

        // C/D layout (32x32, verified m74/m101): col = lane&31 (=n),
        // row(batch) = (reg&3) + 8*(reg>>2) + 4*h
#pragma unroll
        for (int r = 0; r < 16; ++r) {
            int brow = (r & 3) + 8 * (r >> 2) + 4 * h;
            float2 v; v.x = accR[r]; v.y = accI[r];
            wsP[((size_t)s * NB + brow) * NN + n] = v;
        }
    }

    grid.sync();

    // ---- phase 2: reduce (65536 float4 jobs = 2 complex each) ----
    {
        const float4* wsP4 = (const float4*)wsP;
        for (int t = blockIdx.x * 512 + tid; t < NB * NN / 2; t += gthr) {
            float re0 = 0.f, im0 = 0.f, re1 = 0.f, im1 = 0.f;
            for (int s = 0; s < S; ++s) {
                float4 v = wsP4[(size_t)s * (NB * NN / 2) + t];
                re0 += v.x; im0 += v.y; re1 += v.z; im1 += v.w;
            }
            ((float2*)out)[t]          = make_float2(re0, re1);
            ((float2*)(out + HALF))[t] = make_float2(im0, im1);
        }
    }
}

// ---------------------------------------------------------------------------
// Fallback path: the proven R9 3-kernel pipeline (used only if the
// cooperative launch is rejected, e.g. by graph capture).
// ---------------------------------------------------------------------------
__global__ __launch_bounds__(256) void prep_kernel(
    const float* __restrict__ in_re, const float* __restrict__ in_im,
    const float* __restrict__ amp,   const float* __restrict__ phase,
    uint32_t* __restrict__ wsA)
{
    int tid = blockIdx.x * 256 + threadIdx.x;
    prep_body(tid, in_re, in_im, amp, phase, wsA);
}

__global__ __launch_bounds__(512) void gemm_kernel(
    const float* __restrict__ w_re, const float* __restrict__ w_im,
    const uint32_t* __restrict__ wsA, float2* __restrict__ wsP, int steps)
{
    __shared__ float    ldsW[2][2][KB][256];
    __shared__ uint32_t ldsA[2][KB * 32];

    const int tid  = threadIdx.x;
    const int lane = tid & 63;
    const int wave = tid >> 6;
    const int h    = lane >> 5;
    const int l32  = lane & 31;
    const int n    = blockIdx.x * 256 + wave * 32 + l32;
    const int s    = blockIdx.y;
    const int kbase = s * (steps * KB);

    const float* gW_re = w_re + (size_t)kbase * NN + blockIdx.x * 256 + (lane << 2);
    const float* gW_im = w_im + (size_t)kbase * NN + blockIdx.x * 256 + (lane << 2);
    const uint32_t* gA = wsA + (size_t)(kbase >> 2) * 128 + lane;

    f32x16 accR = {};
    f32x16 accI = {};

    auto STAGE = [&](int t, int bb) {
#pragma unroll
        for (int j = 0; j < 4; ++j) {
            int row = j * 8 + wave;
            __builtin_amdgcn_global_load_lds(
                (const __attribute__((address_space(1))) void*)(gW_re + (size_t)(t * KB + row) * NN),
                (__attribute__((address_space(3))) void*)(&ldsW[bb][0][row][0]),
                16, 0, 0);
        }
#pragma unroll
        for (int j = 0; j < 4; ++j) {
            int row = j * 8 + wave;
            __builtin_amdgcn_global_load_lds(
                (const __attribute__((address_space(1))) void*)(gW_im + (size_t)(t * KB + row) * NN),
                (__attribute__((address_space(3))) void*)(&ldsW[bb][1][row][0]),
                16, 0, 0);
        }
#pragma unroll
        for (int j = 0; j < 2; ++j) {
            int c = wave * 2 + j;
            __builtin_amdgcn_global_load_lds(
                (const __attribute__((address_space(1))) void*)(gA + (size_t)t * (KB * 32) + c * 64),
                (__attribute__((address_space(3))) void*)(&ldsA[bb][c * 64]),
                4, 0, 0);
        }
    };

    auto COMPUTE = [&](int bb) {
#pragma unroll
        for (int ss = 0; ss < 4; ++ss) {
            bf16x8 afrag = *(const bf16x8*)&ldsA[bb][ss * 256 + h * 128 + l32 * 4];
            const float* Lre = &ldsW[bb][0][ss * 8 + h * 4][wave * 32 + l32];
            const float* Lim = &ldsW[bb][1][ss * 8 + h * 4][wave * 32 + l32];
            float r0 = Lre[0], r1 = Lre[256], r2 = Lre[512], r3 = Lre[768];
            float i0 = Lim[0], i1 = Lim[256], i2 = Lim[512], i3 = Lim[768];

            unsigned short br0 = f2bf(r0), br1 = f2bf(r1), br2 = f2bf(r2), br3 = f2bf(r3);
            unsigned short bi0 = f2bf(i0), bi1 = f2bf(i1), bi2 = f2bf(i2), bi3 = f2bf(i3);
            bf16x8 bR, bI;
            bR[0] = (short)br0;  bR[1] = (short)(bi0 ^ 0x8000);
            bR[2] = (short)br1;  bR[3] = (short)(bi1 ^ 0x8000);
            bR[4] = (short)br2;  bR[5] = (short)(bi2 ^ 0x8000);
            bR[6] = (short)br3;  bR[7] = (short)(bi3 ^ 0x8000);
            bI[0] = (short)bi0;  bI[1] = (short)br0;
            bI[2] = (short)bi1;  bI[3] = (short)br1;
            bI[4] = (short)bi2;  bI[5] = (short)br2;
            bI[6] = (short)bi3;  bI[7] = (short)br3;

            accR = __builtin_amdgcn_mfma_f32_32x32x16_bf16(afrag, bR, accR, 0, 0, 0);
            accI = __builtin_amdgcn_mfma_f32_32x32x16_bf16(afrag, bI, accI, 0, 0, 0);
        }
    };

    STAGE(0, 0);
    for (int t = 0; t < steps - 1; ++t) {
        STAGE(t + 1, (t + 1) & 1);
        asm volatile("s_waitcnt vmcnt(10)" ::: "memory");
        __builtin_amdgcn_s_barrier();
        COMPUTE(t & 1);
        __builtin_amdgcn_s_barrier();
    }
    asm volatile("s_waitcnt vmcnt(0)" ::: "memory");
    __builtin_amdgcn_s_barrier();
    COMPUTE((steps - 1) & 1);

#pragma unroll
    for (int r = 0; r < 16; ++r) {
        int brow = (r & 3) + 8 * (r >> 2) + 4 * h;
        float2 v; v.x = accR[r]; v.y = accI[r];
        wsP[((size_t)s * NB + brow) * NN + n] = v;
    }
}

__global__ __launch_bounds__(256) void reduce_kernel(
    const float4* __restrict__ wsP, float* __restrict__ out, int S)
{
    int tid = blockIdx.x * 256 + threadIdx.x;
    float re0 = 0.f, im0 = 0.f, re1 = 0.f, im1 = 0.f;
#pragma unroll 8
    for (int s = 0; s < S; ++s) {
        float4 v = wsP[(size_t)s * (NB * NN / 2) + tid];
        re0 += v.x; im0 += v.y; re1 += v.z; im1 += v.w;
    }
    float2* o_re = (float2*)out + tid;
    float2* o_im = (float2*)(out + HALF) + tid;
    *o_re = make_float2(re0, re1);
    *o_im = make_float2(im0, im1);
}

extern "C" void kernel_launch(void* const* d_in, const int* in_sizes, int n_in,
                              void* d_out, int out_size, void* d_ws, size_t ws_size,
                              hipStream_t stream)
{
    const float* in_re  = (const float*)d_in[0];
    const float* in_im  = (const float*)d_in[1];
    const float* w_re   = (const float*)d_in[2];
    const float* w_im   = (const float*)d_in[3];
    const float* amp    = (const float*)d_in[4];
    const float* phase  = (const float*)d_in[5];

    const size_t A_BYTES = (size_t)1024 * 32 * 16;   // 512 KB bf16 A-fragments
    uint32_t* wsA = (uint32_t*)d_ws;
    float2*   wsP = (float2*)((char*)d_ws + A_BYTES);
    float*    outp = (float*)d_out;

    int S = 16;
    while (S > 1 && A_BYTES + (size_t)S * NB * NN * sizeof(float2) > ws_size) S >>= 1;
    int steps = (KC / S) / KB;

    void* args[] = {
        (void*)&in_re, (void*)&in_im, (void*)&amp, (void*)&phase,
        (void*)&w_re, (void*)&w_im,
        (void*)&wsA, (void*)&wsP, (void*)&outp, (void*)&S, (void*)&steps
    };
    hipError_t err = hipLaunchCooperativeKernel(
        (const void*)fused_kernel, dim3(16 * S), dim3(512), args, 0, stream);

    if (err != hipSuccess) {
        // Fallback: proven 3-kernel pipeline.
        prep_kernel<<<dim3((NB * KC) / 256), dim3(256), 0, stream>>>(
            in_re, in_im, amp, phase, wsA);
        gemm_kernel<<<dim3(NN / 256, S), dim3(512), 0, stream>>>(
            w_re, w_im, wsA, wsP, steps);
        reduce_kernel<<<dim3((NB * NN / 2) / 256), dim3(256), 0, stream>>>(
            (const float4*)wsP, outp, S);
    }
}

// Round 6
// 171.115 us; speedup vs baseline: 1.4150x; 1.4150x over previous
//
#include <hip/hip_runtime.h>
#include <cstdint>
#include <cstddef>

// B=32 batch, K=4096 complex input pixels, N=4096 complex outputs.
// out[b,n] = sum_k (e_in[b,k]*ts[k]) * w[k,n]   (complex)
// Real-GEMM formulation, K'=8192 interleaved (re,im):
//   A[b][2k]=m_re, A[b][2k+1]=m_im
//   B_re[2k][n]=w_re, B_re[2k+1][n]=-w_im  -> out_re
//   B_im[2k][n]=w_im, B_im[2k+1][n]= w_re  -> out_im
// OUTPUT (established R5): float32 PLANAR — [re-plane 131072][im-plane 131072].
//
// R11: revert R10's cooperative fusion (grid.sync invalidated XCD L2s ->
// gemm phase ran half speed; non-kernel overhead is harness-fixed).
// Test the W-read RUN-LENGTH hypothesis: 6 variants all cap at ~2.7 TB/s
// delivered; the one constant was <=1 KB contiguous runs strided 16 KB.
// R11 widens the per-block n-tile to 512 (2 KB runs) with S=32 split-K so
// the grid stays 256 blocks. Everything else is R9's proven structure.
#define KC 4096
#define NN 4096
#define NB 32
#define HALF (NB * NN)

typedef __attribute__((ext_vector_type(8))) short  bf16x8;  // 8 bf16 (4 VGPRs)
typedef __attribute__((ext_vector_type(16))) float f32x16;  // 32x32 MFMA acc

__device__ __forceinline__ unsigned short f2bf(float f) {
    union { float f; unsigned u; } v; v.f = f;
    unsigned r = v.u + 0x7fffu + ((v.u >> 16) & 1u);
    return (unsigned short)(r >> 16);
}

// ---------------------------------------------------------------------------
// Kernel 1: modulated[b,k] = e_in[b,k] * (sigmoid(amp[k]) * exp(i*phase[k]))
// bf16 pairs in MFMA-A octet order: k'=2k+(re:0/im:1), octet o=k'>>3 (=k>>2),
// slot r=k'&7; dword index = ((k>>2)*32 + b)*4 + (k&3), re lo16 / im hi16.
// ---------------------------------------------------------------------------
__global__ __launch_bounds__(256) void prep_kernel(
    const float* __restrict__ in_re, const float* __restrict__ in_im,
    const float* __restrict__ amp,   const float* __restrict__ phase,
    uint32_t* __restrict__ wsA)
{
    int tid = blockIdx.x * 256 + threadIdx.x;   // 32*4096 threads
    int b = tid >> 12;
    int k = tid & (KC - 1);
    float er = in_re[tid], ei = in_im[tid];
    float a = amp[k], p = phase[k];
    float s = 1.0f / (1.0f + __expf(-a));
    float sn = __sinf(p);
    float cs = __cosf(p);
    float tr = s * cs, ti = s * sn;
    float mr = er * tr - ei * ti;
    float mi = er * ti + ei * tr;
    uint32_t pk = (uint32_t)f2bf(mr) | ((uint32_t)f2bf(mi) << 16);
    wsA[((((k >> 2) << 5) + b) << 2) | (k & 3)] = pk;
}

// ---------------------------------------------------------------------------
// Kernel 2 (R11): split-K complex GEMM, templated on split count S_.
//   NT  = n-tile = 16*S_   (512 @ S=32: 2 KB contiguous runs; 256 @ S=16)
//   KBk = complex k per step = 512/S_   -> staged bytes/step = 64 KB always
//   grid = (4096/NT) x S_ = 256 blocks always; steps = 8 always.
// Double-buffered LDS (132-136 KB, 1 block/CU), glds staging
// (8 W + AGW A = 9|10 VMEM/wave/step), counted vmcnt so the next tile's
// loads stay in flight across both barriers (T3/T4), raw s_barriers.
// LDS W layout [k][NT] f32: read bank = l32 -> 2-way (free, m136).
// ---------------------------------------------------------------------------
template <int S_>
__global__ __launch_bounds__(512, 2) void gemm_tmpl(
    const float* __restrict__ w_re, const float* __restrict__ w_im,
    const uint32_t* __restrict__ wsA, float2* __restrict__ wsP)
{
    constexpr int KBk  = 512 / S_;       // complex k per step   (16 | 32)
    constexpr int NT   = 16 * S_;        // n-tile               (512 | 256)
    constexpr int CG   = NT / 256;       // col-groups per wave  (2 | 1)
    constexpr int CHR  = NT / 256;       // 1 KB chunks per row  (2 | 1)
    constexpr int PR   = 2 * KBk;        // plane-rows per step  (32 | 64)
    constexpr int PRW  = PR / 8;         // plane-rows per wave  (4 | 8)
    constexpr int AGW  = KBk / 16;       // A-glds per wave      (1 | 2)
    constexpr int SS   = KBk / 8;        // MFMA substeps        (2 | 4)
    constexpr int STEPS = (KC / S_) / KBk;                    // 8

    __shared__ float    ldsW[2][2][KBk][NT];   // [buf][re/im][k][n] 128 KB
    __shared__ uint32_t ldsA[2][KBk * 32];     // [buf][dw]          4|8 KB

    const int tid  = threadIdx.x;
    const int lane = tid & 63;
    const int wave = tid >> 6;      // 0..7
    const int h    = lane >> 5;     // K'-octet half
    const int l32  = lane & 31;
    const int bidx = blockIdx.x;    // n-slice
    const int s    = blockIdx.y;    // k-split
    const int kbase = s * (KC / S_);

    // A staging: wsA dwords for step t = [(kbase>>2)*128 + t*KBk*32, +KBk*32)
    const uint32_t* gA = wsA + (size_t)(kbase >> 2) * 128 + lane;

    f32x16 accR[CG] = {};
    f32x16 accI[CG] = {};

    auto STAGE = [&](int t, int bb) {
#pragma unroll
        for (int i = 0; i < PRW; ++i) {
            int pr    = wave * PRW + i;
            int plane = pr / KBk;          // 0 = re, 1 = im
            int row   = pr % KBk;
            const float* wp = plane ? w_im : w_re;
            const float* gsrc = wp + (size_t)(kbase + t * KBk + row) * NN
                                   + bidx * NT + (lane << 2);
#pragma unroll
            for (int c = 0; c < CHR; ++c) {
                __builtin_amdgcn_global_load_lds(
                    (const __attribute__((address_space(1))) void*)(gsrc + c * 256),
                    (__attribute__((address_space(3))) void*)(&ldsW[bb][plane][row][c * 256]),
                    16, 0, 0);
            }
        }
#pragma unroll
        for (int j = 0; j < AGW; ++j) {
            int c = wave * AGW + j;        // 64-dword chunk index
            __builtin_amdgcn_global_load_lds(
                (const __attribute__((address_space(1))) void*)(gA + (size_t)t * (KBk * 32) + c * 64),
                (__attribute__((address_space(3))) void*)(&ldsA[bb][c * 64]),
                4, 0, 0);
        }
    };

    auto COMPUTE = [&](int bb) {
#pragma unroll
        for (int ss = 0; ss < SS; ++ss) {
            // A fragment: dwords ss*256 + (h*32 + l32)*4 .. +3 (R8-verified)
            bf16x8 afrag = *(const bf16x8*)&ldsA[bb][ss * 256 + h * 128 + l32 * 4];
#pragma unroll
            for (int cg = 0; cg < CG; ++cg) {
                const int col = cg * 256 + wave * 32 + l32;
                const float* Lre = &ldsW[bb][0][ss * 8 + h * 4][col];
                const float* Lim = &ldsW[bb][1][ss * 8 + h * 4][col];
                float r0 = Lre[0], r1 = Lre[NT], r2 = Lre[2 * NT], r3 = Lre[3 * NT];
                float i0 = Lim[0], i1 = Lim[NT], i2 = Lim[2 * NT], i3 = Lim[3 * NT];

                // f2bf(-x) == f2bf(x)^0x8000 exactly (RNE is sign-symmetric).
                unsigned short br0 = f2bf(r0), br1 = f2bf(r1), br2 = f2bf(r2), br3 = f2bf(r3);
                unsigned short bi0 = f2bf(i0), bi1 = f2bf(i1), bi2 = f2bf(i2), bi3 = f2bf(i3);
                bf16x8 bR, bI;
                bR[0] = (short)br0;  bR[1] = (short)(bi0 ^ 0x8000);
                bR[2] = (short)br1;  bR[3] = (short)(bi1 ^ 0x8000);
                bR[4] = (short)br2;  bR[5] = (short)(bi2 ^ 0x8000);
                bR[6] = (short)br3;  bR[7] = (short)(bi3 ^ 0x8000);
                bI[0] = (short)bi0;  bI[1] = (short)br0;
                bI[2] = (short)bi1;  bI[3] = (short)br1;
                bI[4] = (short)bi2;  bI[5] = (short)br2;
                bI[6] = (short)bi3;  bI[7] = (short)br3;

                accR[cg] = __builtin_amdgcn_mfma_f32_32x32x16_bf16(afrag, bR, accR[cg], 0, 0, 0);
                accI[cg] = __builtin_amdgcn_mfma_f32_32x32x16_bf16(afrag, bI, accI[cg], 0, 0, 0);
            }
        }
    };

    STAGE(0, 0);
    for (int t = 0; t < STEPS - 1; ++t) {
        STAGE(t + 1, (t + 1) & 1);
        // Wait own (8+AGW) oldest (tile t) done; tile t+1's stay in flight.
        // vmcnt completes oldest-first (m135), so the count is exact.
        if constexpr (S_ == 32)
            asm volatile("s_waitcnt vmcnt(9)" ::: "memory");
        else
            asm volatile("s_waitcnt vmcnt(10)" ::: "memory");
        __builtin_amdgcn_s_barrier();
        COMPUTE(t & 1);
        __builtin_amdgcn_s_barrier();   // protect buf staged next iteration
    }
    asm volatile("s_waitcnt vmcnt(0)" ::: "memory");
    __builtin_amdgcn_s_barrier();
    COMPUTE((STEPS - 1) & 1);

    // C/D layout (32x32, verified m74/m101): col = lane&31 (=n),
    // row(batch) = (reg&3) + 8*(reg>>2) + 4*h
#pragma unroll
    for (int cg = 0; cg < CG; ++cg) {
        const int n = bidx * NT + cg * 256 + wave * 32 + l32;
#pragma unroll
        for (int r = 0; r < 16; ++r) {
            int brow = (r & 3) + 8 * (r >> 2) + 4 * h;
            float2 v; v.x = accR[cg][r]; v.y = accI[cg][r];
            wsP[((size_t)s * NB + brow) * NN + n] = v;
        }
    }
}

// ---------------------------------------------------------------------------
// Kernel 3: planar output (proven R5): out[b*4096+n]=re, out[HALF+..]=im
// float4 loads (2 complex per thread).
// ---------------------------------------------------------------------------
__global__ __launch_bounds__(256) void reduce_kernel(
    const float4* __restrict__ wsP, float* __restrict__ out, int S)
{
    int tid = blockIdx.x * 256 + threadIdx.x;   // 65536 float4 = 2 complex
    float re0 = 0.f, im0 = 0.f, re1 = 0.f, im1 = 0.f;
#pragma unroll 8
    for (int s = 0; s < S; ++s) {
        float4 v = wsP[(size_t)s * (NB * NN / 2) + tid];
        re0 += v.x; im0 += v.y; re1 += v.z; im1 += v.w;
    }
    float2* o_re = (float2*)out + tid;
    float2* o_im = (float2*)(out + HALF) + tid;
    *o_re = make_float2(re0, re1);
    *o_im = make_float2(im0, im1);
}

extern "C" void kernel_launch(void* const* d_in, const int* in_sizes, int n_in,
                              void* d_out, int out_size, void* d_ws, size_t ws_size,
                              hipStream_t stream)
{
    const float* in_re  = (const float*)d_in[0];
    const float* in_im  = (const float*)d_in[1];
    const float* w_re   = (const float*)d_in[2];
    const float* w_im   = (const float*)d_in[3];
    const float* amp    = (const float*)d_in[4];
    const float* phase  = (const float*)d_in[5];

    const size_t A_BYTES = (size_t)1024 * 32 * 16;   // 512 KB bf16 A-fragments
    uint32_t* wsA = (uint32_t*)d_ws;
    float2*   wsP = (float2*)((char*)d_ws + A_BYTES);

    // Primary: S=32, NT=512 (2 KB runs), wsP 32 MB (proven to fit in R7).
    // Fallback: S=16, NT=256 (= proven R9 config).
    int S = 32;
    if (A_BYTES + (size_t)32 * NB * NN * sizeof(float2) > ws_size) S = 16;

    prep_kernel<<<dim3((NB * KC) / 256), dim3(256), 0, stream>>>(
        in_re, in_im, amp, phase, wsA);

    if (S == 32) {
        gemm_tmpl<32><<<dim3(NN / 512, 32), dim3(512), 0, stream>>>(
            w_re, w_im, wsA, wsP);
    } else {
        gemm_tmpl<16><<<dim3(NN / 256, 16), dim3(512), 0, stream>>>(
            w_re, w_im, wsA, wsP);
    }

    reduce_kernel<<<dim3((NB * NN / 2) / 256), dim3(256), 0, stream>>>(
        (const float4*)wsP, (float*)d_out, S);
}

// Round 8
// 164.481 us; speedup vs baseline: 1.4721x; 1.0403x over previous
//
#include <hip/hip_runtime.h>
#include <cstdint>
#include <cstddef>

// B=32 batch, K=4096 complex input pixels, N=4096 complex outputs.
// out[b,n] = sum_k (e_in[b,k]*ts[k]) * w[k,n]   (complex)
// Real-GEMM formulation, K'=8192 interleaved (re,im):
//   A[b][2k]=m_re, A[b][2k+1]=m_im
//   B_re[2k][n]=w_re, B_re[2k+1][n]=-w_im  -> out_re
//   B_im[2k][n]=w_im, B_im[2k+1][n]= w_re  -> out_im
// OUTPUT (established R5): float32 PLANAR — [re-plane 131072][im-plane 131072].
//
// R13: R12's split-K semaphore was rank-buggy under workspace poison (the
// modulo-16 ticket fires for exactly one arriver but not necessarily the
// LAST when the base is arbitrary -> reduction raced ahead of partials).
// Also its 16-winner tail was ~40us of serial re-reads. Drop the semaphore:
// keep the safe half of the fusion (prep folded block-locally into gemm --
// no wsA roundtrip, no cross-block dependency) + the R5-proven reduce
// kernel. 3 dispatches -> 2. This discriminates the dispatch-overhead
// theory with zero synchronization risk.
#define KC 4096
#define NN 4096
#define NB 32
#define HALF (NB * NN)
#define S_SPLIT 16                       // k-splits
#define KBk 16                           // complex k per step
#define NT 256                           // n-tile per block
#define STEPS ((KC / S_SPLIT) / KBk)     // 16

typedef __attribute__((ext_vector_type(8))) short  bf16x8;  // 8 bf16 (4 VGPRs)
typedef __attribute__((ext_vector_type(16))) float f32x16;  // 32x32 MFMA acc

__device__ __forceinline__ unsigned short f2bf(float f) {
    union { float f; unsigned u; } v; v.f = f;
    unsigned r = v.u + 0x7fffu + ((v.u >> 16) & 1u);
    return (unsigned short)(r >> 16);
}

// ---------------------------------------------------------------------------
// Kernel 1 (fused prep+gemm). Grid (16 n-slices, 16 k-splits) x 512 threads.
//  phase A: block-local prep of this k-slice's A-octets into LDS (32 KB):
//           ts[k] = sigmoid(amp)*exp(i*phase); m = e_in*ts; pack bf16 pairs
//           in MFMA-A octet order (dword = ((k>>2)*32+b)*4 + (k&3),
//           re lo16 / im hi16 -- R1-R4-established layout, local k).
//  phase B: R9-proven gemm loop: W staged [k(16)][n(256)] x {re,im} = 32 KB
//           per step via glds (4/wave/step), double-buffered, counted
//           vmcnt(4), raw s_barriers; 4 MFMA/wave/step.
// LDS: 64 KB W + 32 KB A = 96 KB -> 1 block/CU.
// ---------------------------------------------------------------------------
__global__ __launch_bounds__(512, 2) void fused_gemm(
    const float* __restrict__ in_re, const float* __restrict__ in_im,
    const float* __restrict__ amp,   const float* __restrict__ phase,
    const float* __restrict__ w_re,  const float* __restrict__ w_im,
    float2* __restrict__ wsP)
{
    __shared__ float    ldsW[2][2][KBk][NT];   // [buf][re/im][k][n]  64 KB
    __shared__ uint32_t ldsA[8192];            // full k-slice A      32 KB

    const int tid  = threadIdx.x;
    const int lane = tid & 63;
    const int wave = tid >> 6;      // 0..7
    const int h    = lane >> 5;     // K'-octet half
    const int l32  = lane & 31;
    const int bidx = blockIdx.x;    // n-slice
    const int s    = blockIdx.y;    // k-split
    const int kbase = s * (KC / S_SPLIT);   // 256-complex k-slice base

    // ---- phase A: block-local prep ------------------------------------
    // 512 threads: 2 threads per k (256 k), 16 batches each -> 8192 dwords.
    {
        const int k_local = tid & 255;
        const int b0      = (tid >> 8) * 16;
        const int kg      = kbase + k_local;
        float a = amp[kg], p = phase[kg];
        float sg = 1.0f / (1.0f + __expf(-a));
        float sn = __sinf(p), cs = __cosf(p);
        float tr = sg * cs, ti = sg * sn;
#pragma unroll 4
        for (int b = b0; b < b0 + 16; ++b) {
            float er = in_re[b * KC + kg], ei = in_im[b * KC + kg];
            float mr = er * tr - ei * ti;
            float mi = er * ti + ei * tr;
            ldsA[((k_local >> 2) * 32 + b) * 4 + (k_local & 3)] =
                (uint32_t)f2bf(mr) | ((uint32_t)f2bf(mi) << 16);
        }
    }
    __syncthreads();

    // ---- phase B: gemm ------------------------------------------------
    // W staging: 32 plane-rows/step (2 planes x 16 k), 1 KB each = one glds
    // per row; 8 waves x 4 rows. glds dest = wave-uniform base + lane*16.
    const float* gW[2] = {
        w_re + (size_t)kbase * NN + bidx * NT + (lane << 2),
        w_im + (size_t)kbase * NN + bidx * NT + (lane << 2) };

    f32x16 accR = {};
    f32x16 accI = {};

    auto STAGE = [&](int t, int bb) {
#pragma unroll
        for (int i = 0; i < 4; ++i) {
            int pr    = wave * 4 + i;        // 0..31
            int plane = pr >> 4;             // 0 = re, 1 = im
            int row   = pr & 15;
            __builtin_amdgcn_global_load_lds(
                (const __attribute__((address_space(1))) void*)
                    (gW[plane] + (size_t)(t * KBk + row) * NN),
                (__attribute__((address_space(3))) void*)(&ldsW[bb][plane][row][0]),
                16, 0, 0);
        }
    };

    auto COMPUTE = [&](int t, int bb) {
#pragma unroll
        for (int ss = 0; ss < 2; ++ss) {
            // A fragment: local octet o_s = t*4 + ss*2 + h of this slice.
            const int o_s = t * 4 + ss * 2 + h;
            bf16x8 afrag = *(const bf16x8*)&ldsA[(o_s * 32 + l32) * 4];
            const float* Lre = &ldsW[bb][0][ss * 8 + h * 4][wave * 32 + l32];
            const float* Lim = &ldsW[bb][1][ss * 8 + h * 4][wave * 32 + l32];
            float r0 = Lre[0], r1 = Lre[NT], r2 = Lre[2 * NT], r3 = Lre[3 * NT];
            float i0 = Lim[0], i1 = Lim[NT], i2 = Lim[2 * NT], i3 = Lim[3 * NT];

            // f2bf(-x) == f2bf(x)^0x8000 exactly (RNE is sign-symmetric).
            unsigned short br0 = f2bf(r0), br1 = f2bf(r1), br2 = f2bf(r2), br3 = f2bf(r3);
            unsigned short bi0 = f2bf(i0), bi1 = f2bf(i1), bi2 = f2bf(i2), bi3 = f2bf(i3);
            bf16x8 bR, bI;
            bR[0] = (short)br0;  bR[1] = (short)(bi0 ^ 0x8000);
            bR[2] = (short)br1;  bR[3] = (short)(bi1 ^ 0x8000);
            bR[4] = (short)br2;  bR[5] = (short)(bi2 ^ 0x8000);
            bR[6] = (short)br3;  bR[7] = (short)(bi3 ^ 0x8000);
            bI[0] = (short)bi0;  bI[1] = (short)br0;
            bI[2] = (short)bi1;  bI[3] = (short)br1;
            bI[4] = (short)bi2;  bI[5] = (short)br2;
            bI[6] = (short)bi3;  bI[7] = (short)br3;

            accR = __builtin_amdgcn_mfma_f32_32x32x16_bf16(afrag, bR, accR, 0, 0, 0);
            accI = __builtin_amdgcn_mfma_f32_32x32x16_bf16(afrag, bI, accI, 0, 0, 0);
        }
    };

    STAGE(0, 0);
    for (int t = 0; t < STEPS - 1; ++t) {
        STAGE(t + 1, (t + 1) & 1);
        // Wait own 4 oldest (tile t); tile t+1's 4 stay in flight (m135).
        asm volatile("s_waitcnt vmcnt(4)" ::: "memory");
        __builtin_amdgcn_s_barrier();
        COMPUTE(t, t & 1);
        __builtin_amdgcn_s_barrier();
    }
    asm volatile("s_waitcnt vmcnt(0)" ::: "memory");
    __builtin_amdgcn_s_barrier();
    COMPUTE(STEPS - 1, (STEPS - 1) & 1);

    // Partials. C/D layout (32x32, verified m74/m101): col = lane&31 (=n),
    // row(batch) = (reg&3) + 8*(reg>>2) + 4*h. Normal stores (L3-resident
    // for the reduce pass).
    {
        const int n = bidx * NT + wave * 32 + l32;
#pragma unroll
        for (int r = 0; r < 16; ++r) {
            int brow = (r & 3) + 8 * (r >> 2) + 4 * h;
            float2 v; v.x = accR[r]; v.y = accI[r];
            wsP[((size_t)s * NB + brow) * NN + n] = v;
        }
    }
}

// ---------------------------------------------------------------------------
// Kernel 2: planar output (proven R5): out[b*4096+n]=re, out[HALF+..]=im
// float4 loads (2 complex per thread).
// ---------------------------------------------------------------------------
__global__ __launch_bounds__(256) void reduce_kernel(
    const float4* __restrict__ wsP, float* __restrict__ out)
{
    int tid = blockIdx.x * 256 + threadIdx.x;   // 65536 float4 = 2 complex
    float re0 = 0.f, im0 = 0.f, re1 = 0.f, im1 = 0.f;
#pragma unroll 8
    for (int s = 0; s < S_SPLIT; ++s) {
        float4 v = wsP[(size_t)s * (NB * NN / 2) + tid];
        re0 += v.x; im0 += v.y; re1 += v.z; im1 += v.w;
    }
    float2* o_re = (float2*)out + tid;
    float2* o_im = (float2*)(out + HALF) + tid;
    *o_re = make_float2(re0, re1);
    *o_im = make_float2(im0, im1);
}

extern "C" void kernel_launch(void* const* d_in, const int* in_sizes, int n_in,
                              void* d_out, int out_size, void* d_ws, size_t ws_size,
                              hipStream_t stream)
{
    const float* in_re  = (const float*)d_in[0];
    const float* in_im  = (const float*)d_in[1];
    const float* w_re   = (const float*)d_in[2];
    const float* w_im   = (const float*)d_in[3];
    const float* amp    = (const float*)d_in[4];
    const float* phase  = (const float*)d_in[5];

    float2* wsP = (float2*)d_ws;   // 16 MB split-K partials

    fused_gemm<<<dim3(NN / NT, S_SPLIT), dim3(512), 0, stream>>>(
        in_re, in_im, amp, phase, w_re, w_im, wsP);

    reduce_kernel<<<dim3((NB * NN / 2) / 256), dim3(256), 0, stream>>>(
        (const float4*)wsP, (float*)d_out);
}